// Round 13
// baseline (875.578 us; speedup 1.0000x reference)
//
#include <hip/hip_runtime.h>
#include <math.h>

#define NB 256   // graphs
#define NP 512   // points per graph
#define NH 16    // hidden dim
#define NK 8     // neighbors

__device__ __forceinline__ float elu_f(float x) { return x > 0.0f ? x : expm1f(x); }

__global__ __launch_bounds__(256) void k_encoder(
    const float* __restrict__ x,
    const float* __restrict__ We1, const float* __restrict__ be1,
    const float* __restrict__ We2, const float* __restrict__ be2,
    float* __restrict__ h, float* __restrict__ sq)
{
    int i = blockIdx.x * 256 + threadIdx.x;           // 0 .. NB*NP-1
    float4 xv = reinterpret_cast<const float4*>(x)[i];
    float h1[NH];
#pragma unroll
    for (int o = 0; o < NH; ++o) {
        float a = be1[o];
        a = fmaf(xv.x, We1[0*NH+o], a);
        a = fmaf(xv.y, We1[1*NH+o], a);
        a = fmaf(xv.z, We1[2*NH+o], a);
        a = fmaf(xv.w, We1[3*NH+o], a);
        h1[o] = elu_f(a);
    }
    float hv[NH];
    float s = 0.0f;
#pragma unroll
    for (int o = 0; o < NH; ++o) {
        float a = be2[o];
#pragma unroll
        for (int q = 0; q < NH; ++q) a = fmaf(h1[q], We2[q*NH+o], a);
        a = elu_f(a);
        hv[o] = a;
        s = fmaf(a, a, s);
    }
#pragma unroll
    for (int d = 0; d < NH; d += 4)
        *reinterpret_cast<float4*>(h + (size_t)i*NH + d) =
            make_float4(hv[d], hv[d+1], hv[d+2], hv[d+3]);
    sq[i] = s;
}

// One 1024-thread block per graph (16 waves/CU = 2x round-11 occupancy).
// Two threads per point: thread t handles point p = t&511, scanning the
// j-half [half*256, half*256+256). Each thread's serial dot->d2->insertion
// dependency chain is halved and twice the waves are available to hide it
// (round 9 global-load vs round 11 LDS landing within 2% implicated latency,
// not the load path or raw VALU count). Top-8 lists are merged by inserting
// the partner's sorted list through the same strict-< insertion (ties keep
// the lower-j list -> exact jax.lax.top_k semantics). Edge MLP is split 4+4
// edges across the pair and max-merged (fmax exact). All fp expression
// orders identical to rounds 9/11 -> absmax must stay 0.0.
template<int FINAL>
__global__ __launch_bounds__(1024, 4) void k_conv(
    const float* __restrict__ hin, const float* __restrict__ sqin,
    const float* __restrict__ Wc, const float* __restrict__ bc,
    float* hout, float* sqout,
    const float* __restrict__ Wo1, const float* __restrict__ bo1,
    const float* __restrict__ Wo2, const float* __restrict__ bo2,
    const float* __restrict__ Wo3, const float* __restrict__ bo3,
    float* __restrict__ out)
{
    __shared__ float hs[NP * NH];     // 32 KB feature rows
    __shared__ float sqs[NP];         //  2 KB row norms
    __shared__ float pbd[NP * NK];    // 16 KB partner top-8 d2
    __shared__ int   pbj[NP * NK];    // 16 KB partner top-8 idx (reused to share merged idx)
    __shared__ float fbuf[NP * NH];   // 32 KB half1 partial f

    const int g = blockIdx.x;
    const int t = threadIdx.x;
    const int p = t & (NP - 1);       // point id
    const int half = t >> 9;          // 0: j in [0,256), 1: j in [256,512)
    const int jb = half * (NP / 2);

    // ---- stage full tile (threads 0..511)
    if (t < NP) {
        const float4* hg4 = reinterpret_cast<const float4*>(hin + (size_t)g * NP * NH);
        float4* hs4 = reinterpret_cast<float4*>(hs);
#pragma unroll
        for (int d4 = 0; d4 < 4; ++d4) hs4[t * 4 + d4] = hg4[(size_t)t * 4 + d4];
        sqs[t] = sqin[(size_t)g * NP + t];
    }
    __syncthreads();

    float xi[NH];
#pragma unroll
    for (int d = 0; d < NH; ++d) xi[d] = hs[p * NH + d];
    const float sqi = sqs[p];

    // ---- scan this thread's 256 candidates (strict-< stable insertion)
    float bd[NK]; int bj[NK];
#pragma unroll
    for (int k = 0; k < NK; ++k) { bd[k] = 3.402823466e38f; bj[k] = 0; }

#pragma unroll 4
    for (int jo = 0; jo < NP / 2; ++jo) {
        const int j = jb + jo;
        const float* row = hs + j * NH;
        float dot = 0.0f;
#pragma unroll
        for (int d = 0; d < NH; ++d) dot = fmaf(row[d], xi[d], dot);
        float d2 = sqi + sqs[j] - 2.0f * dot;    // EXACT ref expression order
        if (d2 < bd[NK-1]) {
            float dc = d2; int jc = j;
#pragma unroll
            for (int k = 0; k < NK; ++k) {
                if (dc < bd[k]) {
                    float td = bd[k]; int tj = bj[k];
                    bd[k] = dc; bj[k] = jc; dc = td; jc = tj;
                }
            }
        }
    }

    // ---- half1 publishes its sorted top-8
    if (half) {
#pragma unroll
        for (int k = 0; k < NK; ++k) { pbd[p*NK+k] = bd[k]; pbj[p*NK+k] = bj[k]; }
    }
    __syncthreads();

    // ---- half0 merges partner list (ascending inserts; all partner j > own j,
    //      strict < keeps earlier-j on ties -> stable), then shares idx 4..7
    if (!half) {
#pragma unroll
        for (int k2 = 0; k2 < NK; ++k2) {
            float dc = pbd[p*NK+k2]; int jc = pbj[p*NK+k2];
            if (dc < bd[NK-1]) {
#pragma unroll
                for (int k = 0; k < NK; ++k) {
                    if (dc < bd[k]) {
                        float td = bd[k]; int tj = bj[k];
                        bd[k] = dc; bj[k] = jc; dc = td; jc = tj;
                    }
                }
            }
        }
#pragma unroll
        for (int k = 4; k < NK; ++k) pbj[p*NK+k] = bj[k];   // own slots only, no race
    }
    __syncthreads();

    // ---- edge MLP, 4 edges per thread
    int ej[4];
    if (!half) {
#pragma unroll
        for (int c = 0; c < 4; ++c) ej[c] = bj[c];
    } else {
#pragma unroll
        for (int c = 0; c < 4; ++c) ej[c] = pbj[p*NK+4+c];
    }

    float base[NH];
#pragma unroll
    for (int o = 0; o < NH; ++o) base[o] = bc[o];
#pragma unroll
    for (int d = 0; d < NH; ++d) {
        float xv = xi[d];
#pragma unroll
        for (int o = 0; o < NH; ++o) base[o] = fmaf(xv, Wc[d*NH+o], base[o]);
    }

    float f[NH];
#pragma unroll
    for (int o = 0; o < NH; ++o) f[o] = -3.402823466e38f;
#pragma unroll
    for (int c = 0; c < 4; ++c) {
        const float* rj = hs + ej[c] * NH;
        float m[NH];
#pragma unroll
        for (int o = 0; o < NH; ++o) m[o] = base[o];
#pragma unroll
        for (int d = 0; d < NH; ++d) {
            float dx = rj[d] - xi[d];
#pragma unroll
            for (int o = 0; o < NH; ++o) m[o] = fmaf(dx, Wc[(NH+d)*NH+o], m[o]);
        }
#pragma unroll
        for (int o = 0; o < NH; ++o) f[o] = fmaxf(f[o], elu_f(m[o]));
    }

    if (half) {
#pragma unroll
        for (int d = 0; d < NH; d += 4)
            *reinterpret_cast<float4*>(fbuf + p*NH + d) =
                make_float4(f[d], f[d+1], f[d+2], f[d+3]);
    }
    __syncthreads();

    if constexpr (FINAL == 0) {
        if (!half) {
#pragma unroll
            for (int d = 0; d < NH; ++d) f[d] = fmaxf(f[d], fbuf[p*NH+d]);
            float s = 0.0f;
#pragma unroll
            for (int d = 0; d < NH; ++d) s = fmaf(f[d], f[d], s);
#pragma unroll
            for (int d = 0; d < NH; d += 4)
                *reinterpret_cast<float4*>(hout + (size_t)(g * NP + p) * NH + d) =
                    make_float4(f[d], f[d+1], f[d+2], f[d+3]);
            sqout[(size_t)g * NP + p] = s;
        }
    } else {
        __shared__ float red[8][NH];
        if (!half) {
#pragma unroll
            for (int d = 0; d < NH; ++d) {
                float v = fmaxf(f[d], fbuf[p*NH+d]);
                v += __shfl_down(v, 32);
                v += __shfl_down(v, 16);
                v += __shfl_down(v, 8);
                v += __shfl_down(v, 4);
                v += __shfl_down(v, 2);
                v += __shfl_down(v, 1);
                f[d] = v;
            }
            const int lane = t & 63, w = t >> 6;   // w in 0..7 for t<512
            if (lane == 0) {
#pragma unroll
                for (int d = 0; d < NH; ++d) red[w][d] = f[d];
            }
        }
        __syncthreads();
        if (t == 0) {
            float pooled[NH];
#pragma unroll
            for (int d = 0; d < NH; ++d) {
                float s = red[0][d];
#pragma unroll
                for (int w2 = 1; w2 < 8; ++w2) s += red[w2][d];
                pooled[d] = s * (1.0f/512.0f);
            }
            float o1[8];
#pragma unroll
            for (int o = 0; o < 8; ++o) {
                float a = bo1[o];
#pragma unroll
                for (int q = 0; q < NH; ++q) a = fmaf(pooled[q], Wo1[q*8+o], a);
                o1[o] = elu_f(a);
            }
            float o2[4];
#pragma unroll
            for (int o = 0; o < 4; ++o) {
                float a = bo2[o];
#pragma unroll
                for (int q = 0; q < 8; ++q) a = fmaf(o1[q], Wo2[q*4+o], a);
                o2[o] = elu_f(a);
            }
            float r = bo3[0];
#pragma unroll
            for (int q = 0; q < 4; ++q) r = fmaf(o2[q], Wo3[q], r);
            out[g] = r;                 // output 0: (256,1) float32
            out[NB + g] = (float)g;     // output 1: arange(256) written as float
        }
    }
}

extern "C" void kernel_launch(void* const* d_in, const int* in_sizes, int n_in,
                              void* d_out, int out_size, void* d_ws, size_t ws_size,
                              hipStream_t stream)
{
    const float* x   = (const float*)d_in[0];
    const float* We1 = (const float*)d_in[3];
    const float* be1 = (const float*)d_in[4];
    const float* We2 = (const float*)d_in[5];
    const float* be2 = (const float*)d_in[6];
    const float* Wc  = (const float*)d_in[7];
    const float* bc  = (const float*)d_in[8];
    const float* Wo1 = (const float*)d_in[9];
    const float* bo1 = (const float*)d_in[10];
    const float* Wo2 = (const float*)d_in[11];
    const float* bo2 = (const float*)d_in[12];
    const float* Wo3 = (const float*)d_in[13];
    const float* bo3 = (const float*)d_in[14];
    float* out = (float*)d_out;

    const size_t NPTS = (size_t)NB * NP;
    float* h   = (float*)d_ws;            // NPTS*NH
    float* sq0 = h + NPTS*NH;             // NPTS
    float* f1;
    float* sq1;
    const size_t need = (NPTS*NH + NPTS) * 2 * sizeof(float);
    if (ws_size >= need) {
        f1  = sq0 + NPTS;
        sq1 = f1 + NPTS*NH;
    } else {                               // in-place fallback (LDS-staging-protected)
        f1  = h;
        sq1 = sq0;
    }

    k_encoder<<<dim3((unsigned)(NPTS/256)), dim3(256), 0, stream>>>(
        x, We1, be1, We2, be2, h, sq0);
    k_conv<0><<<dim3(NB), dim3(1024), 0, stream>>>(
        h, sq0, Wc, bc, f1, sq1,
        nullptr, nullptr, nullptr, nullptr, nullptr, nullptr, nullptr);
    k_conv<1><<<dim3(NB), dim3(1024), 0, stream>>>(
        f1, sq1, Wc, bc, nullptr, nullptr,
        Wo1, bo1, Wo2, bo2, Wo3, bo3, out);
}

// Round 16
// 604.099 us; speedup vs baseline: 1.4494x; 1.4494x over previous
//
#include <hip/hip_runtime.h>
#include <math.h>

#define NB 256   // graphs
#define NP 512   // points per graph
#define NH 16    // hidden dim
#define NK 8     // neighbors

__device__ __forceinline__ float elu_f(float x) { return x > 0.0f ? x : expm1f(x); }

__global__ __launch_bounds__(256) void k_encoder(
    const float* __restrict__ x,
    const float* __restrict__ We1, const float* __restrict__ be1,
    const float* __restrict__ We2, const float* __restrict__ be2,
    float* __restrict__ h, float* __restrict__ sq)
{
    int i = blockIdx.x * 256 + threadIdx.x;           // 0 .. NB*NP-1
    float4 xv = reinterpret_cast<const float4*>(x)[i];
    float h1[NH];
#pragma unroll
    for (int o = 0; o < NH; ++o) {
        float a = be1[o];
        a = fmaf(xv.x, We1[0*NH+o], a);
        a = fmaf(xv.y, We1[1*NH+o], a);
        a = fmaf(xv.z, We1[2*NH+o], a);
        a = fmaf(xv.w, We1[3*NH+o], a);
        h1[o] = elu_f(a);
    }
    float hv[NH];
    float s = 0.0f;
#pragma unroll
    for (int o = 0; o < NH; ++o) {
        float a = be2[o];
#pragma unroll
        for (int q = 0; q < NH; ++q) a = fmaf(h1[q], We2[q*NH+o], a);
        a = elu_f(a);
        hv[o] = a;
        s = fmaf(a, a, s);
    }
#pragma unroll
    for (int d = 0; d < NH; d += 4)
        *reinterpret_cast<float4*>(h + (size_t)i*NH + d) =
            make_float4(hv[d], hv[d+1], hv[d+2], hv[d+3]);
    sq[i] = s;
}

// r11 structure (512 thr/block, 1 block/graph — best measured: 270us) with ONE
// change: row reads in the j-scan are float4 (ds_read_b128 x4) instead of 16
// scalar b32. Issue-slot accounting of r9/r11/r13 shows the scan is bound by
// LDS/load ISSUE cost (~93 cyc/wave-j scalar), not FMA (~32 cyc) nor wave
// latency (r13: 2x waves -> 1.5x SLOWER). b128 cuts row-read issue to ~48cyc.
// FMA accumulation order unchanged (d ascending) -> bit-identical d2 -> the
// exact top-k + absmax 0.0 must be preserved.
template<int FINAL>
__global__ __launch_bounds__(512) void k_conv(
    const float* __restrict__ hin, const float* __restrict__ sqin,
    const float* __restrict__ Wc, const float* __restrict__ bc,
    float* hout, float* sqout,
    const float* __restrict__ Wo1, const float* __restrict__ bo1,
    const float* __restrict__ Wo2, const float* __restrict__ bo2,
    const float* __restrict__ Wo3, const float* __restrict__ bo3,
    float* __restrict__ out)
{
    __shared__ float hs[NP * NH];    // 32 KB: this graph's feature rows
    __shared__ float sqs[NP];        //  2 KB: row norms

    const int g = blockIdx.x;
    const int t = threadIdx.x;

    // ---- stage: thread t copies row t (coalesced global read, keeps own row in regs)
    float xi[NH];
    {
        const float4* hg4 = reinterpret_cast<const float4*>(hin + (size_t)g * NP * NH);
        float4* hs4 = reinterpret_cast<float4*>(hs);
#pragma unroll
        for (int d4 = 0; d4 < 4; ++d4) {
            float4 v = hg4[(size_t)t * 4 + d4];
            hs4[t * 4 + d4] = v;
            xi[d4*4+0] = v.x; xi[d4*4+1] = v.y; xi[d4*4+2] = v.z; xi[d4*4+3] = v.w;
        }
    }
    const float sqi = sqin[(size_t)g * NP + t];
    sqs[t] = sqi;
    __syncthreads();

    // ---- top-8 smallest d2, stable ties (earlier index wins) == jax.lax.top_k(-d2, 8)
    float bd[NK]; int bj[NK];
#pragma unroll
    for (int k = 0; k < NK; ++k) { bd[k] = 3.402823466e38f; bj[k] = 0; }

#pragma unroll 4
    for (int j = 0; j < NP; ++j) {
        const float4* row4 = reinterpret_cast<const float4*>(hs + j * NH);
        float4 a0 = row4[0];
        float4 a1 = row4[1];
        float4 a2 = row4[2];
        float4 a3 = row4[3];
        float dot = 0.0f;
        dot = fmaf(a0.x, xi[0],  dot);
        dot = fmaf(a0.y, xi[1],  dot);
        dot = fmaf(a0.z, xi[2],  dot);
        dot = fmaf(a0.w, xi[3],  dot);
        dot = fmaf(a1.x, xi[4],  dot);
        dot = fmaf(a1.y, xi[5],  dot);
        dot = fmaf(a1.z, xi[6],  dot);
        dot = fmaf(a1.w, xi[7],  dot);
        dot = fmaf(a2.x, xi[8],  dot);
        dot = fmaf(a2.y, xi[9],  dot);
        dot = fmaf(a2.z, xi[10], dot);
        dot = fmaf(a2.w, xi[11], dot);
        dot = fmaf(a3.x, xi[12], dot);
        dot = fmaf(a3.y, xi[13], dot);
        dot = fmaf(a3.z, xi[14], dot);
        dot = fmaf(a3.w, xi[15], dot);
        float d2 = sqi + sqs[j] - 2.0f * dot;    // EXACT ref expression order
        if (d2 < bd[NK-1]) {
            float dc = d2; int jc = j;
#pragma unroll
            for (int k = 0; k < NK; ++k) {
                if (dc < bd[k]) {
                    float td = bd[k]; int tj = bj[k];
                    bd[k] = dc; bj[k] = jc; dc = td; jc = tj;
                }
            }
        }
    }

    // ---- edge MLP: m = elu([xi, xj-xi] @ Wc + bc); xi-part shared by all 8 edges
    float base[NH];
#pragma unroll
    for (int o = 0; o < NH; ++o) base[o] = bc[o];
#pragma unroll
    for (int d = 0; d < NH; ++d) {
        float xv = xi[d];
#pragma unroll
        for (int o = 0; o < NH; ++o) base[o] = fmaf(xv, Wc[d*NH+o], base[o]);
    }

    float f[NH];
#pragma unroll
    for (int o = 0; o < NH; ++o) f[o] = -3.402823466e38f;
#pragma unroll
    for (int k = 0; k < NK; ++k) {
        const float4* rj4 = reinterpret_cast<const float4*>(hs + bj[k] * NH);
        float rv[NH];
#pragma unroll
        for (int d4 = 0; d4 < 4; ++d4) {
            float4 v = rj4[d4];
            rv[d4*4+0] = v.x; rv[d4*4+1] = v.y; rv[d4*4+2] = v.z; rv[d4*4+3] = v.w;
        }
        float m[NH];
#pragma unroll
        for (int o = 0; o < NH; ++o) m[o] = base[o];
#pragma unroll
        for (int d = 0; d < NH; ++d) {
            float dx = rv[d] - xi[d];
#pragma unroll
            for (int o = 0; o < NH; ++o) m[o] = fmaf(dx, Wc[(NH+d)*NH+o], m[o]);
        }
#pragma unroll
        for (int o = 0; o < NH; ++o) f[o] = fmaxf(f[o], elu_f(m[o]));
    }

    if (FINAL == 0) {
        float s = 0.0f;
#pragma unroll
        for (int d = 0; d < NH; ++d) s = fmaf(f[d], f[d], s);
#pragma unroll
        for (int d = 0; d < NH; d += 4)
            *reinterpret_cast<float4*>(hout + (size_t)(g * NP + t) * NH + d) =
                make_float4(f[d], f[d+1], f[d+2], f[d+3]);
        sqout[(size_t)g * NP + t] = s;
    } else {
        __shared__ float red[8][NH];
#pragma unroll
        for (int d = 0; d < NH; ++d) {
            float v = f[d];
            v += __shfl_down(v, 32);
            v += __shfl_down(v, 16);
            v += __shfl_down(v, 8);
            v += __shfl_down(v, 4);
            v += __shfl_down(v, 2);
            v += __shfl_down(v, 1);
            f[d] = v;
        }
        const int lane = t & 63, w = t >> 6;
        if (lane == 0) {
#pragma unroll
            for (int d = 0; d < NH; ++d) red[w][d] = f[d];
        }
        __syncthreads();
        if (t == 0) {
            float pooled[NH];
#pragma unroll
            for (int d = 0; d < NH; ++d) {
                float s = red[0][d];
#pragma unroll
                for (int w2 = 1; w2 < 8; ++w2) s += red[w2][d];
                pooled[d] = s * (1.0f/512.0f);
            }
            float o1[8];
#pragma unroll
            for (int o = 0; o < 8; ++o) {
                float a = bo1[o];
#pragma unroll
                for (int q = 0; q < NH; ++q) a = fmaf(pooled[q], Wo1[q*8+o], a);
                o1[o] = elu_f(a);
            }
            float o2[4];
#pragma unroll
            for (int o = 0; o < 4; ++o) {
                float a = bo2[o];
#pragma unroll
                for (int q = 0; q < 8; ++q) a = fmaf(o1[q], Wo2[q*4+o], a);
                o2[o] = elu_f(a);
            }
            float r = bo3[0];
#pragma unroll
            for (int q = 0; q < 4; ++q) r = fmaf(o2[q], Wo3[q], r);
            out[g] = r;                 // output 0: (256,1) float32
            out[NB + g] = (float)g;     // output 1: arange(256) written as float
        }
    }
}

extern "C" void kernel_launch(void* const* d_in, const int* in_sizes, int n_in,
                              void* d_out, int out_size, void* d_ws, size_t ws_size,
                              hipStream_t stream)
{
    const float* x   = (const float*)d_in[0];
    const float* We1 = (const float*)d_in[3];
    const float* be1 = (const float*)d_in[4];
    const float* We2 = (const float*)d_in[5];
    const float* be2 = (const float*)d_in[6];
    const float* Wc  = (const float*)d_in[7];
    const float* bc  = (const float*)d_in[8];
    const float* Wo1 = (const float*)d_in[9];
    const float* bo1 = (const float*)d_in[10];
    const float* Wo2 = (const float*)d_in[11];
    const float* bo2 = (const float*)d_in[12];
    const float* Wo3 = (const float*)d_in[13];
    const float* bo3 = (const float*)d_in[14];
    float* out = (float*)d_out;

    const size_t NPTS = (size_t)NB * NP;
    float* h   = (float*)d_ws;            // NPTS*NH
    float* sq0 = h + NPTS*NH;             // NPTS
    float* f1;
    float* sq1;
    const size_t need = (NPTS*NH + NPTS) * 2 * sizeof(float);
    if (ws_size >= need) {
        f1  = sq0 + NPTS;
        sq1 = f1 + NPTS*NH;
    } else {                               // in-place fallback (LDS-staging-protected)
        f1  = h;
        sq1 = sq0;
    }

    k_encoder<<<dim3((unsigned)(NPTS/256)), dim3(256), 0, stream>>>(
        x, We1, be1, We2, be2, h, sq0);
    k_conv<0><<<dim3(NB), dim3(512), 0, stream>>>(
        h, sq0, Wc, bc, f1, sq1,
        nullptr, nullptr, nullptr, nullptr, nullptr, nullptr, nullptr);
    k_conv<1><<<dim3(NB), dim3(512), 0, stream>>>(
        f1, sq1, Wc, bc, nullptr, nullptr,
        Wo1, bo1, Wo2, bo2, Wo3, bo3, out);
}